// Round 1
// baseline (60.966 us; speedup 1.0000x reference)
//
#include <hip/hip_runtime.h>
#include <hip/hip_bf16.h>

typedef float f32x4 __attribute__((ext_vector_type(4)));
typedef __bf16 bf16x8 __attribute__((ext_vector_type(8)));

#define DEMB 128
// LDS W1 transposed: w1t[n][k], n=0..63 (hidden), k=0..255, row stride 264 (pad 8)
// stride 264*2B = 528B, 16B-aligned; read pattern gives 8 bank-start groups x 8 lanes
// = conflict-free floor for ds_read_b128.
#define W1T_STRIDE 264

__global__ __launch_bounds__(256) void edge_mlp_kernel(
    const float* __restrict__ src_embs,
    const float* __restrict__ dst_embs,
    const int* __restrict__ src_ids,
    const int* __restrict__ dst_ids,
    const float* __restrict__ W1,
    const float* __restrict__ b1,
    const float* __restrict__ W2,
    const float* __restrict__ b2,
    float* __restrict__ out,
    int n_edges, int n_groups)
{
    __shared__ __bf16 w1t[64 * W1T_STRIDE];

    // Stage W1 (f32 [256][64] row-major) -> bf16 transposed [64][256] in LDS.
    // Coalesced global read; one-time scattered 2B LDS writes are negligible.
    for (int s = threadIdx.x; s < 256 * 64; s += 256) {
        int k = s >> 6;     // 0..255
        int n = s & 63;     // 0..63
        w1t[n * W1T_STRIDE + k] = (__bf16)W1[s];
    }
    __syncthreads();

    const int lane = threadIdx.x & 63;
    const int el = lane & 15;   // edge-within-group (A rows) / n-within-tile (B cols)
    const int gk = lane >> 4;   // k-subgroup 0..3

    // Hoisted layer-2 params: lane handles hidden units n_t = 16t + el
    float b1v[4], w2v[4];
#pragma unroll
    for (int t = 0; t < 4; ++t) {
        b1v[t] = b1[16 * t + el];
        w2v[t] = W2[16 * t + el];
    }
    const float bias2 = b2[0];

    const int gw0 = blockIdx.x * 4 + (threadIdx.x >> 6);
    const int gstride = gridDim.x * 4;

    for (int g = gw0; g < n_groups; g += gstride) {
        const int e_base = g * 16;
        int e = e_base + el;
        if (e >= n_edges) e = n_edges - 1;   // clamp loads; stores guarded below
        const long long sid = src_ids[e];
        const long long did = dst_ids[e];
        const float* sp = src_embs + sid * DEMB + gk * 8;
        const float* dp = dst_embs + did * DEMB + gk * 8;

        f32x4 acc[4] = {{0.f,0.f,0.f,0.f},{0.f,0.f,0.f,0.f},
                        {0.f,0.f,0.f,0.f},{0.f,0.f,0.f,0.f}};

#pragma unroll
        for (int kk = 0; kk < 8; ++kk) {
            // A fragment: lane holds x[edge = el][k = kk*32 + gk*8 + e], e=0..7
            const float* ap = (kk < 4) ? (sp + kk * 32) : (dp + (kk - 4) * 32);
            f32x4 f0 = *reinterpret_cast<const f32x4*>(ap);
            f32x4 f1 = *reinterpret_cast<const f32x4*>(ap + 4);
            bf16x8 a;
#pragma unroll
            for (int j = 0; j < 4; ++j) {
                a[j]     = (__bf16)f0[j];
                a[4 + j] = (__bf16)f1[j];
            }
#pragma unroll
            for (int t = 0; t < 4; ++t) {
                // B fragment: W1t[n = 16t+el][k = kk*32 + gk*8 + e], 8 contiguous bf16
                const bf16x8 bfrag = *reinterpret_cast<const bf16x8*>(
                    &w1t[(16 * t + el) * W1T_STRIDE + kk * 32 + gk * 8]);
                acc[t] = __builtin_amdgcn_mfma_f32_16x16x32_bf16(a, bfrag, acc[t], 0, 0, 0);
            }
        }

        // Layer 2: h = relu(acc + b1); logit = h . W2 + b2
        // C/D layout (verified): col = lane&15 (hidden n part), row = gk*4 + r (edge)
        float s0[4];
#pragma unroll
        for (int r = 0; r < 4; ++r) {
            float v = 0.f;
#pragma unroll
            for (int t = 0; t < 4; ++t) {
                float h = acc[t][r] + b1v[t];
                h = fmaxf(h, 0.f);
                v = fmaf(h, w2v[t], v);
            }
            // reduce over the 16 lanes of this gk-group (64 hidden units total)
#pragma unroll
            for (int m = 1; m < 16; m <<= 1) v += __shfl_xor(v, m, 64);
            s0[r] = v + bias2;
        }
        const int row0 = e_base + gk * 4;
        if (el == 0) {
            if (row0 + 4 <= n_edges) {
                f32x4 o = {s0[0], s0[1], s0[2], s0[3]};
                *reinterpret_cast<f32x4*>(out + row0) = o;
            } else {
#pragma unroll
                for (int r = 0; r < 4; ++r)
                    if (row0 + r < n_edges) out[row0 + r] = s0[r];
            }
        }
    }
}

extern "C" void kernel_launch(void* const* d_in, const int* in_sizes, int n_in,
                              void* d_out, int out_size, void* d_ws, size_t ws_size,
                              hipStream_t stream) {
    const float* src_embs = (const float*)d_in[0];
    const float* dst_embs = (const float*)d_in[1];
    const int*   src_ids  = (const int*)d_in[2];
    const int*   dst_ids  = (const int*)d_in[3];
    const float* W1 = (const float*)d_in[4];
    const float* b1 = (const float*)d_in[5];
    const float* W2 = (const float*)d_in[6];
    const float* b2 = (const float*)d_in[7];
    float* out = (float*)d_out;

    const int n_edges  = in_sizes[2];
    const int n_groups = (n_edges + 15) / 16;   // 18750 for 300000 (exact)
    int blocks = (n_groups + 3) / 4;
    if (blocks > 1024) blocks = 1024;           // persistent: amortize W1 staging

    edge_mlp_kernel<<<blocks, 256, 0, stream>>>(
        src_embs, dst_embs, src_ids, dst_ids, W1, b1, W2, b2, out,
        n_edges, n_groups);
}

// Round 2
// 56.493 us; speedup vs baseline: 1.0792x; 1.0792x over previous
//
#include <hip/hip_runtime.h>
#include <hip/hip_bf16.h>

typedef float f32x4 __attribute__((ext_vector_type(4)));
typedef __bf16 bf16x8 __attribute__((ext_vector_type(8)));

#define DEMB 128
#define HIDDEN 64
#define W1T_STRIDE 264   // 256 + 8 pad; 528B row stride, 16B-aligned

// ---------------- Phase 1: per-node partials (dense skinny GEMM) ----------------
// spart[n] = src_embs[n] @ W1[0:128, :]   (100K x 128 @ 128 x 64)
// dpart[n] = dst_embs[n] @ W1[128:256, :]
__global__ __launch_bounds__(256) void node_part_kernel(
    const float* __restrict__ src_embs,
    const float* __restrict__ dst_embs,
    const float* __restrict__ W1,
    float* __restrict__ spart,
    float* __restrict__ dpart,
    int n_tiles)   // nodes/16 per table
{
    __shared__ __bf16 w1t[HIDDEN * W1T_STRIDE];
    for (int s = threadIdx.x; s < 256 * HIDDEN; s += 256) {
        int k = s >> 6;
        int n = s & 63;
        w1t[n * W1T_STRIDE + k] = (__bf16)W1[s];
    }
    __syncthreads();

    const int lane = threadIdx.x & 63;
    const int el = lane & 15;   // node-within-tile / n-within-tile
    const int gk = lane >> 4;   // k-subgroup

    const int w0 = blockIdx.x * 4 + (threadIdx.x >> 6);
    const int wstride = gridDim.x * 4;
    const int total = 2 * n_tiles;

    for (int tt = w0; tt < total; tt += wstride) {
        const int table = (tt >= n_tiles) ? 1 : 0;
        const int tile = tt - table * n_tiles;
        const float* E = table ? dst_embs : src_embs;
        float* P = table ? dpart : spart;
        const int nbase = tile * 16;
        const float* rp = E + (long long)(nbase + el) * DEMB + gk * 8;
        const int kofs = table * 128;

        f32x4 acc[4] = {{0.f,0.f,0.f,0.f},{0.f,0.f,0.f,0.f},
                        {0.f,0.f,0.f,0.f},{0.f,0.f,0.f,0.f}};
#pragma unroll
        for (int kk = 0; kk < 4; ++kk) {
            f32x4 f0 = *reinterpret_cast<const f32x4*>(rp + kk * 32);
            f32x4 f1 = *reinterpret_cast<const f32x4*>(rp + kk * 32 + 4);
            bf16x8 a;
#pragma unroll
            for (int j = 0; j < 4; ++j) { a[j] = (__bf16)f0[j]; a[4+j] = (__bf16)f1[j]; }
#pragma unroll
            for (int t = 0; t < 4; ++t) {
                const bf16x8 bfrag = *reinterpret_cast<const bf16x8*>(
                    &w1t[(16 * t + el) * W1T_STRIDE + kofs + kk * 32 + gk * 8]);
                acc[t] = __builtin_amdgcn_mfma_f32_16x16x32_bf16(a, bfrag, acc[t], 0, 0, 0);
            }
        }
        // C/D: col = lane&15 (hidden unit 16t+el), row = gk*4 + r (node)
#pragma unroll
        for (int r = 0; r < 4; ++r) {
#pragma unroll
            for (int t = 0; t < 4; ++t)
                P[(long long)(nbase + gk * 4 + r) * HIDDEN + 16 * t + el] = acc[t][r];
        }
    }
}

// ---------------- Phase 2: per-edge gather of partials + MLP tail ----------------
__global__ __launch_bounds__(256) void edge_tail_kernel(
    const float* __restrict__ spart,
    const float* __restrict__ dpart,
    const int* __restrict__ src_ids,
    const int* __restrict__ dst_ids,
    const float* __restrict__ b1,
    const float* __restrict__ W2,
    const float* __restrict__ b2,
    float* __restrict__ out,
    int n_edges)
{
    const int lane = threadIdx.x & 63;
    const int c = lane & 15;          // f32x4 chunk within hidden dim
    const f32x4 b1v = *reinterpret_cast<const f32x4*>(b1 + c * 4);
    const f32x4 w2v = *reinterpret_cast<const f32x4*>(W2 + c * 4);
    const float bias2 = b2[0];

    int gid = (blockIdx.x * blockDim.x + threadIdx.x) >> 4;   // one edge per 16 lanes
    const int gstride = (gridDim.x * blockDim.x) >> 4;

    for (int e = gid; e < n_edges; e += gstride) {
        const long long sid = src_ids[e];
        const long long did = dst_ids[e];
        f32x4 s4 = *reinterpret_cast<const f32x4*>(spart + sid * HIDDEN + c * 4);
        f32x4 d4 = *reinterpret_cast<const f32x4*>(dpart + did * HIDDEN + c * 4);
        float v = 0.f;
#pragma unroll
        for (int j = 0; j < 4; ++j) {
            float h = s4[j] + d4[j] + b1v[j];
            h = fmaxf(h, 0.f);
            v = fmaf(h, w2v[j], v);
        }
#pragma unroll
        for (int m = 1; m < 16; m <<= 1) v += __shfl_xor(v, m, 64);
        if (c == 0) out[e] = v + bias2;
    }
}

// ---------------- Fallback (round-1 proven kernel) if ws too small ----------------
__global__ __launch_bounds__(256) void edge_mlp_kernel(
    const float* __restrict__ src_embs,
    const float* __restrict__ dst_embs,
    const int* __restrict__ src_ids,
    const int* __restrict__ dst_ids,
    const float* __restrict__ W1,
    const float* __restrict__ b1,
    const float* __restrict__ W2,
    const float* __restrict__ b2,
    float* __restrict__ out,
    int n_edges, int n_groups)
{
    __shared__ __bf16 w1t[64 * W1T_STRIDE];
    for (int s = threadIdx.x; s < 256 * 64; s += 256) {
        int k = s >> 6;
        int n = s & 63;
        w1t[n * W1T_STRIDE + k] = (__bf16)W1[s];
    }
    __syncthreads();

    const int lane = threadIdx.x & 63;
    const int el = lane & 15;
    const int gk = lane >> 4;

    float b1v[4], w2v[4];
#pragma unroll
    for (int t = 0; t < 4; ++t) { b1v[t] = b1[16 * t + el]; w2v[t] = W2[16 * t + el]; }
    const float bias2 = b2[0];

    const int gw0 = blockIdx.x * 4 + (threadIdx.x >> 6);
    const int gstride = gridDim.x * 4;

    for (int g = gw0; g < n_groups; g += gstride) {
        const int e_base = g * 16;
        int e = e_base + el;
        if (e >= n_edges) e = n_edges - 1;
        const long long sid = src_ids[e];
        const long long did = dst_ids[e];
        const float* sp = src_embs + sid * DEMB + gk * 8;
        const float* dp = dst_embs + did * DEMB + gk * 8;

        f32x4 acc[4] = {{0.f,0.f,0.f,0.f},{0.f,0.f,0.f,0.f},
                        {0.f,0.f,0.f,0.f},{0.f,0.f,0.f,0.f}};
#pragma unroll
        for (int kk = 0; kk < 8; ++kk) {
            const float* ap = (kk < 4) ? (sp + kk * 32) : (dp + (kk - 4) * 32);
            f32x4 f0 = *reinterpret_cast<const f32x4*>(ap);
            f32x4 f1 = *reinterpret_cast<const f32x4*>(ap + 4);
            bf16x8 a;
#pragma unroll
            for (int j = 0; j < 4; ++j) { a[j] = (__bf16)f0[j]; a[4+j] = (__bf16)f1[j]; }
#pragma unroll
            for (int t = 0; t < 4; ++t) {
                const bf16x8 bfrag = *reinterpret_cast<const bf16x8*>(
                    &w1t[(16 * t + el) * W1T_STRIDE + kk * 32 + gk * 8]);
                acc[t] = __builtin_amdgcn_mfma_f32_16x16x32_bf16(a, bfrag, acc[t], 0, 0, 0);
            }
        }
        float s0[4];
#pragma unroll
        for (int r = 0; r < 4; ++r) {
            float v = 0.f;
#pragma unroll
            for (int t = 0; t < 4; ++t) {
                float h = acc[t][r] + b1v[t];
                h = fmaxf(h, 0.f);
                v = fmaf(h, w2v[t], v);
            }
#pragma unroll
            for (int m = 1; m < 16; m <<= 1) v += __shfl_xor(v, m, 64);
            s0[r] = v + bias2;
        }
        const int row0 = e_base + gk * 4;
        if (el == 0) {
            if (row0 + 4 <= n_edges) {
                f32x4 o = {s0[0], s0[1], s0[2], s0[3]};
                *reinterpret_cast<f32x4*>(out + row0) = o;
            } else {
#pragma unroll
                for (int r = 0; r < 4; ++r)
                    if (row0 + r < n_edges) out[row0 + r] = s0[r];
            }
        }
    }
}

extern "C" void kernel_launch(void* const* d_in, const int* in_sizes, int n_in,
                              void* d_out, int out_size, void* d_ws, size_t ws_size,
                              hipStream_t stream) {
    const float* src_embs = (const float*)d_in[0];
    const float* dst_embs = (const float*)d_in[1];
    const int*   src_ids  = (const int*)d_in[2];
    const int*   dst_ids  = (const int*)d_in[3];
    const float* W1 = (const float*)d_in[4];
    const float* b1 = (const float*)d_in[5];
    const float* W2 = (const float*)d_in[6];
    const float* b2 = (const float*)d_in[7];
    float* out = (float*)d_out;

    const int n_edges = in_sizes[2];
    const int n_nodes = in_sizes[0] / DEMB;           // 100000
    const size_t part_elems = (size_t)n_nodes * HIDDEN;
    const size_t need = 2 * part_elems * sizeof(float);  // 51.2 MB

    if (ws_size >= need && (n_nodes % 16) == 0) {
        float* spart = (float*)d_ws;
        float* dpart = spart + part_elems;
        const int n_tiles = n_nodes / 16;             // 6250

        int blocks1 = (2 * n_tiles + 3) / 4;
        if (blocks1 > 1024) blocks1 = 1024;
        node_part_kernel<<<blocks1, 256, 0, stream>>>(
            src_embs, dst_embs, W1, spart, dpart, n_tiles);

        int groups_per_block = 256 / 16;              // 16 edges per block-iter
        int blocks2 = (n_edges + groups_per_block - 1) / groups_per_block;
        if (blocks2 > 2048) blocks2 = 2048;
        edge_tail_kernel<<<blocks2, 256, 0, stream>>>(
            spart, dpart, src_ids, dst_ids, b1, W2, b2, out, n_edges);
    } else {
        const int n_groups = (n_edges + 15) / 16;
        int blocks = (n_groups + 3) / 4;
        if (blocks > 1024) blocks = 1024;
        edge_mlp_kernel<<<blocks, 256, 0, stream>>>(
            src_embs, dst_embs, src_ids, dst_ids, W1, b1, W2, b2, out,
            n_edges, n_groups);
    }
}